// Round 8
// baseline (112.064 us; speedup 1.0000x reference)
//
#include <hip/hip_runtime.h>
#include <hip/hip_bf16.h>
#include <stdint.h>

#define SDIM 1024
#define BATCH 4
#define NH 16
#define HDIM 64
#define KDIM 1024
#define N_QKV 3072
#define EMB 1024

typedef uint16_t u16;
typedef __attribute__((ext_vector_type(4))) float f32x4;
typedef __attribute__((ext_vector_type(8))) short bf16x8;
typedef __attribute__((ext_vector_type(8))) unsigned short u16x8;

__device__ __forceinline__ u16 f2bf(float f) {
  union { float f; uint32_t u; } x; x.f = f;
  uint32_t r = x.u + 0x7FFFu + ((x.u >> 16) & 1u);
  return (u16)(r >> 16);
}

__device__ __forceinline__ float bf2f(u16 b) {
  union { uint32_t u; float f; } x; x.u = ((uint32_t)b) << 16;
  return x.f;
}

__device__ __forceinline__ void gload_lds16(const u16* g, u16* l) {
  __builtin_amdgcn_global_load_lds(
      (const __attribute__((address_space(1))) unsigned int*)g,
      (__attribute__((address_space(3))) unsigned int*)l, 16, 0, 0);
}

// ---------------- merged f32 -> bf16 conversion ----------------
#define N8_X  524288
#define N8_WQ 393216
#define N8_WO 131072
__global__ void cvt3_kernel(const float* __restrict__ a, const float* __restrict__ b,
                            const float* __restrict__ c,
                            u16* __restrict__ oa, u16* __restrict__ ob, u16* __restrict__ oc) {
  const int total = N8_X + N8_WQ + N8_WO;
  int stride = gridDim.x * blockDim.x;
  for (int i = blockIdx.x * blockDim.x + threadIdx.x; i < total; i += stride) {
    const float* s; u16* d; int j;
    if (i < N8_X)            { s = a; d = oa; j = i; }
    else if (i < N8_X + N8_WQ){ s = b; d = ob; j = i - N8_X; }
    else                     { s = c; d = oc; j = i - N8_X - N8_WQ; }
    const float4* s4 = (const float4*)s + (size_t)j * 2;
    float4 u = s4[0], v = s4[1];
    u16x8 o;
    o[0] = f2bf(u.x); o[1] = f2bf(u.y); o[2] = f2bf(u.z); o[3] = f2bf(u.w);
    o[4] = f2bf(v.x); o[5] = f2bf(v.y); o[6] = f2bf(v.z); o[7] = f2bf(v.w);
    ((u16x8*)d)[j] = o;
  }
}

// ---------------- GEMM1: 256x256, BK=32, ring-4 counted-vmcnt + wm3 ----------------
// blocks 0..191: GEMM tiles (16 M x 12 N). blocks 192..703: wm3 (512 x 2 tiles).
// LDS: 4 ring slots x (A 256x32 + B 256x32) bf16 = 4 x 32KB = 128KB.
// Stage tile t+2 while computing t; end-of-kt: vmcnt(4) + s_barrier (never drain-0 mid-loop).
__global__ __launch_bounds__(512, 1) void gemm_qkv_wm3(
    const u16* __restrict__ A, const u16* __restrict__ Bm,
    const float* __restrict__ bias,
    u16* __restrict__ Qh, u16* __restrict__ Kh, u16* __restrict__ Vt,
    const int* __restrict__ mask, const float* __restrict__ wts, u16* __restrict__ wm3)
{
  __shared__ char smem[131072];
  const int tid = threadIdx.x;

  if (blockIdx.x < 192) {
    // ---------- GEMM part ----------
    const int gid = blockIdx.x;
    const int brow = (gid & 15) * 256, bcol = (gid >> 4) * 256;
    const int wid = tid >> 6, lane = tid & 63;
    const int g = lane >> 4, c = lane & 15;
    const int wr = wid >> 2, wc = wid & 3;        // 2 M-groups x 4 N-groups
    const int cg = g ^ (c & 3);                   // swizzled chunk for fragment reads

    // staging: A tile 256x32 = 1024 16B-chunks (4 chunks/row); 2 loads/thread; B same
    const u16* asrc[2]; const u16* bsrc[2]; int doff[2];
    #pragma unroll
    for (int j = 0; j < 2; ++j) {
      int i = j * 512 + tid;
      int row = i >> 2, sch = (i & 3) ^ (row & 3);
      asrc[j] = A  + (size_t)(brow + row) * KDIM + sch * 8;
      bsrc[j] = Bm + (size_t)(bcol + row) * KDIM + sch * 8;
      doff[j] = (j * 512 + wid * 64) * 16;        // wave-uniform LDS byte offset
    }

    auto stage = [&](int kt, int slot) {
      char* base = smem + slot * 32768;
      #pragma unroll
      for (int j = 0; j < 2; ++j)
        gload_lds16(asrc[j] + kt * 32, (u16*)(base + doff[j]));
      #pragma unroll
      for (int j = 0; j < 2; ++j)
        gload_lds16(bsrc[j] + kt * 32, (u16*)(base + 16384 + doff[j]));
    };

    f32x4 acc[8][4] = {};

    stage(0, 0);
    stage(1, 1);
    asm volatile("s_waitcnt vmcnt(4)" ::: "memory");
    __builtin_amdgcn_s_barrier();
    __builtin_amdgcn_sched_barrier(0);

    for (int kt = 0; kt < 32; ++kt) {
      if (kt + 2 < 32) stage(kt + 2, (kt + 2) & 3);

      const char* As = smem + (kt & 3) * 32768;
      const char* Bs = As + 16384;

      bf16x8 af[8], bfr[4];
      #pragma unroll
      for (int m = 0; m < 8; ++m) {
        int row = wr * 128 + m * 16 + c;
        af[m] = *(const bf16x8*)(As + (row << 6) + (cg << 4));
      }
      #pragma unroll
      for (int n = 0; n < 4; ++n) {
        int row = wc * 64 + n * 16 + c;
        bfr[n] = *(const bf16x8*)(Bs + (row << 6) + (cg << 4));
      }

      __builtin_amdgcn_s_setprio(1);
      #pragma unroll
      for (int m = 0; m < 8; ++m)
        #pragma unroll
        for (int n = 0; n < 4; ++n)
          acc[m][n] = __builtin_amdgcn_mfma_f32_16x16x32_bf16(
              af[m], bfr[n], acc[m][n], 0, 0, 0);
      __builtin_amdgcn_s_setprio(0);

      if (kt < 31) {
        if (kt + 2 < 32) asm volatile("s_waitcnt vmcnt(4)" ::: "memory");
        else             asm volatile("s_waitcnt vmcnt(0)" ::: "memory");
        __builtin_amdgcn_s_barrier();
        __builtin_amdgcn_sched_barrier(0);
      }
    }

    // routed epilogue
    #pragma unroll
    for (int m = 0; m < 8; ++m) {
      #pragma unroll
      for (int n = 0; n < 4; ++n) {
        int col = bcol + wc * 64 + n * 16 + c;
        float bv = bias[col];
        int h = col / 192;
        int rem = col - h * 192;
        int sec = rem >> 6, d = rem & 63;
        #pragma unroll
        for (int r = 0; r < 4; ++r) {
          int row = brow + wr * 128 + m * 16 + g * 4 + r;
          int b = row >> 10, sl = row & 1023;
          float v = acc[m][n][r] + bv;
          if (sec == 0)
            Qh[((size_t)(b * NH + h) * SDIM + sl) * HDIM + d] = f2bf(v * 0.125f);
          else if (sec == 1)
            Kh[((size_t)(b * NH + h) * SDIM + sl) * HDIM + d] = f2bf(v);
          else
            Vt[((size_t)(b * NH + h) * HDIM + d) * SDIM + sl] = f2bf(v);
        }
      }
    }
  } else {
    // ---------- wm3 part: 2 tiles per block, 512 threads ----------
    const int wmid = blockIdx.x - 192;            // 0..511
    const size_t SS = (size_t)SDIM * SDIM;
    int   (*mt)[69] = (int(*)[69])smem;             // [q][k]  64x69
    float (*wt)[69] = (float(*)[69])(smem + 17664); // [k][q]  64x69

    #pragma unroll
    for (int tt = 0; tt < 2; ++tt) {
      const int id = wmid * 2 + tt;               // 0..1023
      const int kt = id & 15, qt = (id >> 4) & 15, b = id >> 8;
      const int q0 = qt * 64, k0 = kt * 64;
      if (tt) __syncthreads();

      #pragma unroll
      for (int j = 0; j < 2; ++j) {
        int idx = j * 512 + tid;
        int row = idx >> 4, c4 = idx & 15;
        int4 m4 = *(const int4*)(mask + (size_t)b * SS + (size_t)(q0 + row) * SDIM + k0 + c4 * 4);
        mt[row][c4 * 4 + 0] = m4.x; mt[row][c4 * 4 + 1] = m4.y;
        mt[row][c4 * 4 + 2] = m4.z; mt[row][c4 * 4 + 3] = m4.w;
        float4 w4 = *(const float4*)(wts + (size_t)b * SS + (size_t)(k0 + row) * SDIM + q0 + c4 * 4);
        wt[row][c4 * 4 + 0] = w4.x; wt[row][c4 * 4 + 1] = w4.y;
        wt[row][c4 * 4 + 2] = w4.z; wt[row][c4 * 4 + 3] = w4.w;
      }
      __syncthreads();

      // fragment-ordered write: thread -> (wid2, half, lane)
      const int wid2 = tid >> 7, hf = (tid >> 6) & 1, lane = tid & 63;
      const int g2 = lane >> 4, c2 = lane & 15;
      const int ql = wid2 * 16 + c2;
      u16x8 o;
      #pragma unroll
      for (int e = 0; e < 8; ++e) {
        int kl = 8 * g2 + 4 * (e >> 2) + (e & 3) + 32 * hf;
        o[e] = mt[ql][kl] ? f2bf(wt[kl][ql]) : (u16)0;
      }
      size_t off = ((((size_t)(b * 16 + qt) * 4 + wid2) * 16 + kt)) * 1024 + lane * 16 + hf * 8;
      *(u16x8*)(wm3 + off) = o;
    }
  }
}

// ---------------- GEMM2 (swizzled LDS, 2-phase 128^2) ----------------
__global__ __launch_bounds__(256) void gemm_bt(
    const u16* __restrict__ A, const u16* __restrict__ Bm,
    const float* __restrict__ bias, float* __restrict__ C,
    int M, int N, int K)
{
  __shared__ u16 As[128 * 64];
  __shared__ u16 Bs[128 * 64];
  const int tid = threadIdx.x;
  const int wid = tid >> 6, lane = tid & 63;
  const int g = lane >> 4, c = lane & 15, cx = c & 7;
  const int wrow = (wid >> 1) * 64, wcol = (wid & 1) * 64;
  const int brow = blockIdx.x * 128, bcol = blockIdx.y * 128;

  const u16* asrc[4]; const u16* bsrc[4]; u16* adst[4]; u16* bdst[4];
  #pragma unroll
  for (int j = 0; j < 4; ++j) {
    int ci = j * 256 + tid;
    int row = ci >> 3, sch = (ci & 7) ^ (row & 7);
    asrc[j] = A  + (size_t)(brow + row) * K + sch * 8;
    bsrc[j] = Bm + (size_t)(bcol + row) * K + sch * 8;
    adst[j] = As + (j * 256 + wid * 64) * 8;
    bdst[j] = Bs + (j * 256 + wid * 64) * 8;
  }

  f32x4 acc[4][4] = {};
  const char* Asc = (const char*)As;
  const char* Bsc = (const char*)Bs;

  for (int kt = 0; kt < K / 64; ++kt) {
    #pragma unroll
    for (int j = 0; j < 4; ++j) {
      gload_lds16(asrc[j] + kt * 64, adst[j]);
      gload_lds16(bsrc[j] + kt * 64, bdst[j]);
    }
    __syncthreads();

    bf16x8 af[2][4], bfr[2][4];
    #pragma unroll
    for (int kk = 0; kk < 2; ++kk)
      #pragma unroll
      for (int i = 0; i < 4; ++i) {
        int cha = ((kk << 2) + g) ^ cx;
        af[kk][i]  = *(const bf16x8*)(Asc + ((wrow + i * 16 + c) << 7) + (cha << 4));
        bfr[kk][i] = *(const bf16x8*)(Bsc + ((wcol + i * 16 + c) << 7) + (cha << 4));
      }
    #pragma unroll
    for (int kk = 0; kk < 2; ++kk)
      #pragma unroll
      for (int mi = 0; mi < 4; ++mi)
        #pragma unroll
        for (int ni = 0; ni < 4; ++ni)
          acc[mi][ni] = __builtin_amdgcn_mfma_f32_16x16x32_bf16(
              af[kk][mi], bfr[kk][ni], acc[mi][ni], 0, 0, 0);
    __syncthreads();
  }

  #pragma unroll
  for (int mi = 0; mi < 4; ++mi)
    #pragma unroll
    for (int ni = 0; ni < 4; ++ni) {
      int col = bcol + wcol + ni * 16 + c;
      float bv = bias[col];
      #pragma unroll
      for (int r = 0; r < 4; ++r) {
        int row = brow + wrow + mi * 16 + g * 4 + r;
        C[(size_t)row * N + col] = acc[mi][ni][r] + bv;
      }
    }
}

// ---------------- attention: in-register P (swapped QK^T + K-row permutation) ----------------
__global__ __launch_bounds__(256, 4) void attn_kernel(
    const u16* __restrict__ Qh, const u16* __restrict__ Kh, const u16* __restrict__ Vt,
    const u16* __restrict__ wm3, u16* __restrict__ vals)
{
  int bid = blockIdx.x;
  int swz = (bid & 7) * 128 + (bid >> 3);
  const int qt = swz & 15, bh = swz >> 4;
  const int h = bh & 15, b = bh >> 4;

  const int tid = threadIdx.x;
  const int wid = tid >> 6, lane = tid & 63;
  const int g = lane >> 4, c = lane & 15;
  const int qloc = qt * 64 + wid * 16;

  __shared__ u16 Kb[2][4096];
  __shared__ u16 Vb[2][4096];

  const u16* qp = Qh + ((size_t)bh * SDIM + qloc + c) * HDIM;
  bf16x8 qa0 = *(const bf16x8*)(qp + g * 8);
  bf16x8 qa1 = *(const bf16x8*)(qp + 32 + g * 8);

  const u16* kbase = Kh + (size_t)bh * SDIM * HDIM;
  const u16* vbase = Vt + (size_t)bh * HDIM * SDIM;
  const u16* wbase = wm3 + (((size_t)(b * 16 + qt) * 4 + wid) * 16) * 1024 + lane * 16;

  float l_run = 0.f;
  f32x4 acc_o[4] = {};

  auto fsw = [](int row) { return ((row ^ (row >> 3)) & 7) ^ ((row & 1) << 2); };

  int kro[4], kxr[4], vro[4], vxr[4];
  #pragma unroll
  for (int st = 0; st < 4; ++st) {
    int kr = ((c >> 2) << 3) + ((st & 1) << 2) + (c & 3) + ((st >> 1) << 5);
    kro[st] = kr << 7;
    kxr[st] = fsw(kr);
  }
  #pragma unroll
  for (int dt = 0; dt < 4; ++dt) {
    int vr = dt * 16 + c;
    vro[dt] = vr << 7;
    vxr[dt] = fsw(vr);
  }

  auto stage = [&](int buf, int kt) {
    const int k0 = kt * 64;
    #pragma unroll
    for (int j = 0; j < 2; ++j) {
      int i = j * 256 + tid;
      int row = i >> 3;
      int sch = (i & 7) ^ (((row ^ (row >> 3)) & 7) ^ ((row & 1) << 2));
      gload_lds16(kbase + (size_t)(k0 + row) * HDIM + sch * 8,
                  &Kb[buf][(size_t)(j * 256 + wid * 64) * 8]);
      gload_lds16(vbase + (size_t)row * SDIM + k0 + sch * 8,
                  &Vb[buf][(size_t)(j * 256 + wid * 64) * 8]);
    }
  };

  stage(0, 0);
  __syncthreads();
  int cur = 0;

  for (int kt = 0; kt < 16; ++kt) {
    if (kt < 15) stage(cur ^ 1, kt + 1);

    u16x8 w0 = *(const u16x8*)(wbase + kt * 1024);
    u16x8 w1 = *(const u16x8*)(wbase + kt * 1024 + 8);

    const char* kb = (const char*)&Kb[cur][0];
    const char* vb = (const char*)&Vb[cur][0];

    f32x4 sc[4];
    #pragma unroll
    for (int st = 0; st < 4; ++st) {
      bf16x8 ka0 = *(const bf16x8*)(kb + kro[st] + ((g ^ kxr[st]) << 4));
      bf16x8 ka1 = *(const bf16x8*)(kb + kro[st] + (((4 + g) ^ kxr[st]) << 4));
      f32x4 z = {};
      z = __builtin_amdgcn_mfma_f32_16x16x32_bf16(ka0, qa0, z, 0, 0, 0);
      z = __builtin_amdgcn_mfma_f32_16x16x32_bf16(ka1, qa1, z, 0, 0, 0);
      sc[st] = z;
    }

    float p[4][4];
    #pragma unroll
    for (int st = 0; st < 4; ++st) {
      #pragma unroll
      for (int r = 0; r < 4; ++r) {
        u16 wv = (st < 2) ? ((const u16*)&w0)[st * 4 + r]
                          : ((const u16*)&w1)[(st - 2) * 4 + r];
        float pv = bf2f(wv) * __expf(sc[st][r]);
        p[st][r] = pv;
        l_run += pv;
      }
    }

    uint32_t pk[8];
    #pragma unroll
    for (int i = 0; i < 8; ++i) {
      float lo = p[i >> 1][(i & 1) * 2], hi = p[i >> 1][(i & 1) * 2 + 1];
      asm("v_cvt_pk_bf16_f32 %0, %1, %2" : "=v"(pk[i]) : "v"(lo), "v"(hi));
    }
    union PA { uint32_t u[4]; bf16x8 v; } a0, a1;
    #pragma unroll
    for (int i = 0; i < 4; ++i) { a0.u[i] = pk[i]; a1.u[i] = pk[4 + i]; }

    #pragma unroll
    for (int dt = 0; dt < 4; ++dt) {
      bf16x8 vb0 = *(const bf16x8*)(vb + vro[dt] + ((g ^ vxr[dt]) << 4));
      bf16x8 vb1 = *(const bf16x8*)(vb + vro[dt] + (((4 + g) ^ vxr[dt]) << 4));
      acc_o[dt] = __builtin_amdgcn_mfma_f32_16x16x32_bf16(a0.v, vb0, acc_o[dt], 0, 0, 0);
      acc_o[dt] = __builtin_amdgcn_mfma_f32_16x16x32_bf16(a1.v, vb1, acc_o[dt], 0, 0, 0);
    }

    __syncthreads();
    cur ^= 1;
  }

  l_run += __shfl_xor(l_run, 16);
  l_run += __shfl_xor(l_run, 32);

  float inv[4];
  #pragma unroll
  for (int r = 0; r < 4; ++r)
    inv[r] = 1.0f / __shfl(l_run, g * 4 + r);

  #pragma unroll
  for (int dt = 0; dt < 4; ++dt)
    #pragma unroll
    for (int r = 0; r < 4; ++r) {
      int row = b * SDIM + qloc + g * 4 + r;
      vals[(size_t)row * EMB + h * HDIM + dt * 16 + c] = f2bf(acc_o[dt][r] * inv[r]);
    }
}

extern "C" void kernel_launch(void* const* d_in, const int* in_sizes, int n_in,
                              void* d_out, int out_size, void* d_ws, size_t ws_size,
                              hipStream_t stream) {
  const float* x     = (const float*)d_in[0];
  const int*   mask  = (const int*)d_in[1];
  const float* wts   = (const float*)d_in[2];
  const float* W_qkv = (const float*)d_in[3];
  const float* b_qkv = (const float*)d_in[4];
  const float* W_o   = (const float*)d_in[5];
  const float* b_o   = (const float*)d_in[6];
  float* out = (float*)d_out;

  char* ws = (char*)d_ws;
  u16* xb   = (u16*)(ws);                     //  8 MB x bf16
  u16* wqb  = (u16*)(ws + (8ull  << 20));     //  6 MB W_qkv bf16
  u16* wob  = (u16*)(ws + (14ull << 20));     //  2 MB W_o bf16
  u16* Qh   = (u16*)(ws + (16ull << 20));     //  8 MB [bh][s][64]
  u16* Kh   = (u16*)(ws + (24ull << 20));     //  8 MB [bh][s][64]
  u16* Vt   = (u16*)(ws + (32ull << 20));     //  8 MB [bh][64][s]
  u16* valb = (u16*)(ws + (40ull << 20));     //  8 MB attn out bf16
  u16* wm3b = (u16*)d_out;                    //  8 MB scratch in d_out (overwritten by gemm_bt)

  cvt3_kernel<<<2048, 256, 0, stream>>>(x, W_qkv, W_o, xb, wqb, wob);

  gemm_qkv_wm3<<<704, 512, 0, stream>>>(xb, wqb, b_qkv, Qh, Kh, Vt, mask, wts, wm3b);

  attn_kernel<<<1024, 256, 0, stream>>>(Qh, Kh, Vt, wm3b, valb);

  dim3 g3(32, 8);
  gemm_bt<<<g3, 256, 0, stream>>>(valb, wob, b_o, out, BATCH * SDIM, EMB, KDIM);
}

// Round 9
// 106.794 us; speedup vs baseline: 1.0493x; 1.0493x over previous
//
#include <hip/hip_runtime.h>
#include <hip/hip_bf16.h>
#include <stdint.h>

#define SDIM 1024
#define BATCH 4
#define NH 16
#define HDIM 64
#define KDIM 1024
#define N_QKV 3072
#define EMB 1024

typedef uint16_t u16;
typedef __attribute__((ext_vector_type(4))) float f32x4;
typedef __attribute__((ext_vector_type(8))) short bf16x8;
typedef __attribute__((ext_vector_type(8))) unsigned short u16x8;

__device__ __forceinline__ u16 f2bf(float f) {
  union { float f; uint32_t u; } x; x.f = f;
  uint32_t r = x.u + 0x7FFFu + ((x.u >> 16) & 1u);
  return (u16)(r >> 16);
}

__device__ __forceinline__ float bf2f(u16 b) {
  union { uint32_t u; float f; } x; x.u = ((uint32_t)b) << 16;
  return x.f;
}

__device__ __forceinline__ void gload_lds16(const u16* g, u16* l) {
  __builtin_amdgcn_global_load_lds(
      (const __attribute__((address_space(1))) unsigned int*)g,
      (__attribute__((address_space(3))) unsigned int*)l, 16, 0, 0);
}

// ---------------- merged f32 -> bf16 conversion ----------------
#define N8_X  524288
#define N8_WQ 393216
#define N8_WO 131072
__global__ void cvt3_kernel(const float* __restrict__ a, const float* __restrict__ b,
                            const float* __restrict__ c,
                            u16* __restrict__ oa, u16* __restrict__ ob, u16* __restrict__ oc) {
  const int total = N8_X + N8_WQ + N8_WO;
  int stride = gridDim.x * blockDim.x;
  for (int i = blockIdx.x * blockDim.x + threadIdx.x; i < total; i += stride) {
    const float* s; u16* d; int j;
    if (i < N8_X)            { s = a; d = oa; j = i; }
    else if (i < N8_X + N8_WQ){ s = b; d = ob; j = i - N8_X; }
    else                     { s = c; d = oc; j = i - N8_X - N8_WQ; }
    const float4* s4 = (const float4*)s + (size_t)j * 2;
    float4 u = s4[0], v = s4[1];
    u16x8 o;
    o[0] = f2bf(u.x); o[1] = f2bf(u.y); o[2] = f2bf(u.z); o[3] = f2bf(u.w);
    o[4] = f2bf(v.x); o[5] = f2bf(v.y); o[6] = f2bf(v.z); o[7] = f2bf(v.w);
    ((u16x8*)d)[j] = o;
  }
}

// ---------------- GEMM1: 256x192 tiles (256 blocks = 1/CU) + wm3 quota per block ----
// Every block: [prefetch GEMM tile0] -> [4 wm3 tiles] -> [2-phase GEMM, BK=64].
// LDS: 2 slots x (A 256x64 = 32KB + B 192x64 = 24KB) = 114688 B; wm3 buffers live
// inside slot1's region (57344..92671), freed before stage(1).
__global__ __launch_bounds__(512, 1) void gemm_qkv_wm3(
    const u16* __restrict__ A, const u16* __restrict__ Bm,
    const float* __restrict__ bias,
    u16* __restrict__ Qh, u16* __restrict__ Kh, u16* __restrict__ Vt,
    const int* __restrict__ mask, const float* __restrict__ wts, u16* __restrict__ wm3)
{
  __shared__ char smem[131072];
  const int tid = threadIdx.x;
  const int gid = blockIdx.x;                    // 0..255
  const int brow = (gid & 15) * 256, bcol = (gid >> 4) * 192;
  const int wid = tid >> 6, lane = tid & 63;
  const int g = lane >> 4, c = lane & 15, cx = c & 7;
  const int wr = wid & 3, wc = wid >> 2;         // 4 M-groups x 2 N-groups

  // staging addresses: A 2048 chunks (4/thread), B 1536 chunks (3/thread)
  const u16* asrc[4]; int adoff[4];
  #pragma unroll
  for (int j = 0; j < 4; ++j) {
    int i = j * 512 + tid;
    int row = i >> 3, sch = (i & 7) ^ (row & 7);
    asrc[j] = A + (size_t)(brow + row) * KDIM + sch * 8;
    adoff[j] = (j * 512 + wid * 64) * 16;
  }
  const u16* bsrc[3]; int bdoff[3];
  #pragma unroll
  for (int j = 0; j < 3; ++j) {
    int i = j * 512 + tid;
    int row = i >> 3, sch = (i & 7) ^ (row & 7);
    bsrc[j] = Bm + (size_t)(bcol + row) * KDIM + sch * 8;
    bdoff[j] = 32768 + (j * 512 + wid * 64) * 16;
  }

  auto stage = [&](int kt, int slot) {
    char* base = smem + slot * 57344;
    #pragma unroll
    for (int j = 0; j < 4; ++j)
      gload_lds16(asrc[j] + kt * 64, (u16*)(base + adoff[j]));
    #pragma unroll
    for (int j = 0; j < 3; ++j)
      gload_lds16(bsrc[j] + kt * 64, (u16*)(base + bdoff[j]));
  };

  // ---- prefetch GEMM tile 0 into slot 0 (disjoint from wm3 buffers) ----
  stage(0, 0);

  // ---- wm3 phase: 4 tiles per block, buffers in slot1 region ----
  {
    const size_t SS = (size_t)SDIM * SDIM;
    int   (*mt)[69] = (int(*)[69])(smem + 57344);            // [q][k] 64x69
    float (*wt)[69] = (float(*)[69])(smem + 57344 + 17664);  // [k][q] 64x69

    #pragma unroll
    for (int tt = 0; tt < 4; ++tt) {
      const int id = gid * 4 + tt;               // 0..1023
      const int kt = id & 15, qt = (id >> 4) & 15, b = id >> 8;
      const int q0 = qt * 64, k0 = kt * 64;
      if (tt) __syncthreads();                   // prev writer done before restage

      #pragma unroll
      for (int j = 0; j < 2; ++j) {
        int idx = j * 512 + tid;
        int row = idx >> 4, c4 = idx & 15;
        int4 m4 = *(const int4*)(mask + (size_t)b * SS + (size_t)(q0 + row) * SDIM + k0 + c4 * 4);
        mt[row][c4 * 4 + 0] = m4.x; mt[row][c4 * 4 + 1] = m4.y;
        mt[row][c4 * 4 + 2] = m4.z; mt[row][c4 * 4 + 3] = m4.w;
        float4 w4 = *(const float4*)(wts + (size_t)b * SS + (size_t)(k0 + row) * SDIM + q0 + c4 * 4);
        wt[row][c4 * 4 + 0] = w4.x; wt[row][c4 * 4 + 1] = w4.y;
        wt[row][c4 * 4 + 2] = w4.z; wt[row][c4 * 4 + 3] = w4.w;
      }
      __syncthreads();

      // fragment-ordered write: thread -> (wid2, half, lane)
      const int wid2 = tid >> 7, hf = (tid >> 6) & 1, lane2 = tid & 63;
      const int g2 = lane2 >> 4, c2 = lane2 & 15;
      const int ql = wid2 * 16 + c2;
      u16x8 o;
      #pragma unroll
      for (int e = 0; e < 8; ++e) {
        int kl = 8 * g2 + 4 * (e >> 2) + (e & 3) + 32 * hf;
        o[e] = mt[ql][kl] ? f2bf(wt[kl][ql]) : (u16)0;
      }
      size_t off = ((((size_t)(b * 16 + qt) * 4 + wid2) * 16 + kt)) * 1024 + lane2 * 16 + hf * 8;
      *(u16x8*)(wm3 + off) = o;
    }
    __syncthreads();                             // wm3 done; slot1 region free
  }

  // ---- GEMM: 2-phase, BK=64, per-wave 64x96 (4 M-frag x 6 N-frag) ----
  f32x4 acc[4][6] = {};

  for (int kt = 0; kt < 16; ++kt) {
    if (kt < 15) stage(kt + 1, (kt + 1) & 1);

    const char* As = smem + (kt & 1) * 57344;
    const char* Bs = As + 32768;

    #pragma unroll
    for (int kk = 0; kk < 2; ++kk) {
      bf16x8 af[4], bfr[6];
      #pragma unroll
      for (int m = 0; m < 4; ++m) {
        int row = wr * 64 + m * 16 + c;
        af[m] = *(const bf16x8*)(As + (row << 7) + ((((kk << 2) + g) ^ cx) << 4));
      }
      #pragma unroll
      for (int n = 0; n < 6; ++n) {
        int row = wc * 96 + n * 16 + c;
        bfr[n] = *(const bf16x8*)(Bs + (row << 7) + ((((kk << 2) + g) ^ cx) << 4));
      }
      __builtin_amdgcn_s_setprio(1);
      #pragma unroll
      for (int m = 0; m < 4; ++m)
        #pragma unroll
        for (int n = 0; n < 6; ++n)
          acc[m][n] = __builtin_amdgcn_mfma_f32_16x16x32_bf16(
              af[m], bfr[n], acc[m][n], 0, 0, 0);
      __builtin_amdgcn_s_setprio(0);
    }
    __syncthreads();
  }

  // routed epilogue
  #pragma unroll
  for (int m = 0; m < 4; ++m) {
    #pragma unroll
    for (int n = 0; n < 6; ++n) {
      int col = bcol + wc * 96 + n * 16 + c;
      float bv = bias[col];
      int h = col / 192;
      int rem = col - h * 192;
      int sec = rem >> 6, d = rem & 63;
      #pragma unroll
      for (int r = 0; r < 4; ++r) {
        int row = brow + wr * 64 + m * 16 + g * 4 + r;
        int b = row >> 10, sl = row & 1023;
        float v = acc[m][n][r] + bv;
        if (sec == 0)
          Qh[((size_t)(b * NH + h) * SDIM + sl) * HDIM + d] = f2bf(v * 0.125f);
        else if (sec == 1)
          Kh[((size_t)(b * NH + h) * SDIM + sl) * HDIM + d] = f2bf(v);
        else
          Vt[((size_t)(b * NH + h) * HDIM + d) * SDIM + sl] = f2bf(v);
      }
    }
  }
}

// ---------------- GEMM2 (swizzled LDS, 2-phase 128^2) ----------------
__global__ __launch_bounds__(256) void gemm_bt(
    const u16* __restrict__ A, const u16* __restrict__ Bm,
    const float* __restrict__ bias, float* __restrict__ C,
    int M, int N, int K)
{
  __shared__ u16 As[128 * 64];
  __shared__ u16 Bs[128 * 64];
  const int tid = threadIdx.x;
  const int wid = tid >> 6, lane = tid & 63;
  const int g = lane >> 4, c = lane & 15, cx = c & 7;
  const int wrow = (wid >> 1) * 64, wcol = (wid & 1) * 64;
  const int brow = blockIdx.x * 128, bcol = blockIdx.y * 128;

  const u16* asrc[4]; const u16* bsrc[4]; u16* adst[4]; u16* bdst[4];
  #pragma unroll
  for (int j = 0; j < 4; ++j) {
    int ci = j * 256 + tid;
    int row = ci >> 3, sch = (ci & 7) ^ (row & 7);
    asrc[j] = A  + (size_t)(brow + row) * K + sch * 8;
    bsrc[j] = Bm + (size_t)(bcol + row) * K + sch * 8;
    adst[j] = As + (j * 256 + wid * 64) * 8;
    bdst[j] = Bs + (j * 256 + wid * 64) * 8;
  }

  f32x4 acc[4][4] = {};
  const char* Asc = (const char*)As;
  const char* Bsc = (const char*)Bs;

  for (int kt = 0; kt < K / 64; ++kt) {
    #pragma unroll
    for (int j = 0; j < 4; ++j) {
      gload_lds16(asrc[j] + kt * 64, adst[j]);
      gload_lds16(bsrc[j] + kt * 64, bdst[j]);
    }
    __syncthreads();

    bf16x8 af[2][4], bfr[2][4];
    #pragma unroll
    for (int kk = 0; kk < 2; ++kk)
      #pragma unroll
      for (int i = 0; i < 4; ++i) {
        int cha = ((kk << 2) + g) ^ cx;
        af[kk][i]  = *(const bf16x8*)(Asc + ((wrow + i * 16 + c) << 7) + (cha << 4));
        bfr[kk][i] = *(const bf16x8*)(Bsc + ((wcol + i * 16 + c) << 7) + (cha << 4));
      }
    #pragma unroll
    for (int kk = 0; kk < 2; ++kk)
      #pragma unroll
      for (int mi = 0; mi < 4; ++mi)
        #pragma unroll
        for (int ni = 0; ni < 4; ++ni)
          acc[mi][ni] = __builtin_amdgcn_mfma_f32_16x16x32_bf16(
              af[kk][mi], bfr[kk][ni], acc[mi][ni], 0, 0, 0);
    __syncthreads();
  }

  #pragma unroll
  for (int mi = 0; mi < 4; ++mi)
    #pragma unroll
    for (int ni = 0; ni < 4; ++ni) {
      int col = bcol + wcol + ni * 16 + c;
      float bv = bias[col];
      #pragma unroll
      for (int r = 0; r < 4; ++r) {
        int row = brow + wrow + mi * 16 + g * 4 + r;
        C[(size_t)row * N + col] = acc[mi][ni][r] + bv;
      }
    }
}

// ---------------- attention: in-register P (swapped QK^T + K-row permutation) ----------------
__global__ __launch_bounds__(256, 4) void attn_kernel(
    const u16* __restrict__ Qh, const u16* __restrict__ Kh, const u16* __restrict__ Vt,
    const u16* __restrict__ wm3, u16* __restrict__ vals)
{
  int bid = blockIdx.x;
  int swz = (bid & 7) * 128 + (bid >> 3);
  const int qt = swz & 15, bh = swz >> 4;
  const int h = bh & 15, b = bh >> 4;

  const int tid = threadIdx.x;
  const int wid = tid >> 6, lane = tid & 63;
  const int g = lane >> 4, c = lane & 15;
  const int qloc = qt * 64 + wid * 16;

  __shared__ u16 Kb[2][4096];
  __shared__ u16 Vb[2][4096];

  const u16* qp = Qh + ((size_t)bh * SDIM + qloc + c) * HDIM;
  bf16x8 qa0 = *(const bf16x8*)(qp + g * 8);
  bf16x8 qa1 = *(const bf16x8*)(qp + 32 + g * 8);

  const u16* kbase = Kh + (size_t)bh * SDIM * HDIM;
  const u16* vbase = Vt + (size_t)bh * HDIM * SDIM;
  const u16* wbase = wm3 + (((size_t)(b * 16 + qt) * 4 + wid) * 16) * 1024 + lane * 16;

  float l_run = 0.f;
  f32x4 acc_o[4] = {};

  auto fsw = [](int row) { return ((row ^ (row >> 3)) & 7) ^ ((row & 1) << 2); };

  int kro[4], kxr[4], vro[4], vxr[4];
  #pragma unroll
  for (int st = 0; st < 4; ++st) {
    int kr = ((c >> 2) << 3) + ((st & 1) << 2) + (c & 3) + ((st >> 1) << 5);
    kro[st] = kr << 7;
    kxr[st] = fsw(kr);
  }
  #pragma unroll
  for (int dt = 0; dt < 4; ++dt) {
    int vr = dt * 16 + c;
    vro[dt] = vr << 7;
    vxr[dt] = fsw(vr);
  }

  auto stage = [&](int buf, int kt) {
    const int k0 = kt * 64;
    #pragma unroll
    for (int j = 0; j < 2; ++j) {
      int i = j * 256 + tid;
      int row = i >> 3;
      int sch = (i & 7) ^ (((row ^ (row >> 3)) & 7) ^ ((row & 1) << 2));
      gload_lds16(kbase + (size_t)(k0 + row) * HDIM + sch * 8,
                  &Kb[buf][(size_t)(j * 256 + wid * 64) * 8]);
      gload_lds16(vbase + (size_t)row * SDIM + k0 + sch * 8,
                  &Vb[buf][(size_t)(j * 256 + wid * 64) * 8]);
    }
  };

  stage(0, 0);
  __syncthreads();
  int cur = 0;

  for (int kt = 0; kt < 16; ++kt) {
    if (kt < 15) stage(cur ^ 1, kt + 1);

    u16x8 w0 = *(const u16x8*)(wbase + kt * 1024);
    u16x8 w1 = *(const u16x8*)(wbase + kt * 1024 + 8);

    const char* kb = (const char*)&Kb[cur][0];
    const char* vb = (const char*)&Vb[cur][0];

    f32x4 sc[4];
    #pragma unroll
    for (int st = 0; st < 4; ++st) {
      bf16x8 ka0 = *(const bf16x8*)(kb + kro[st] + ((g ^ kxr[st]) << 4));
      bf16x8 ka1 = *(const bf16x8*)(kb + kro[st] + (((4 + g) ^ kxr[st]) << 4));
      f32x4 z = {};
      z = __builtin_amdgcn_mfma_f32_16x16x32_bf16(ka0, qa0, z, 0, 0, 0);
      z = __builtin_amdgcn_mfma_f32_16x16x32_bf16(ka1, qa1, z, 0, 0, 0);
      sc[st] = z;
    }

    float p[4][4];
    #pragma unroll
    for (int st = 0; st < 4; ++st) {
      #pragma unroll
      for (int r = 0; r < 4; ++r) {
        u16 wv = (st < 2) ? ((const u16*)&w0)[st * 4 + r]
                          : ((const u16*)&w1)[(st - 2) * 4 + r];
        float pv = bf2f(wv) * __expf(sc[st][r]);
        p[st][r] = pv;
        l_run += pv;
      }
    }

    uint32_t pk[8];
    #pragma unroll
    for (int i = 0; i < 8; ++i) {
      float lo = p[i >> 1][(i & 1) * 2], hi = p[i >> 1][(i & 1) * 2 + 1];
      asm("v_cvt_pk_bf16_f32 %0, %1, %2" : "=v"(pk[i]) : "v"(lo), "v"(hi));
    }
    union PA { uint32_t u[4]; bf16x8 v; } a0, a1;
    #pragma unroll
    for (int i = 0; i < 4; ++i) { a0.u[i] = pk[i]; a1.u[i] = pk[4 + i]; }

    #pragma unroll
    for (int dt = 0; dt < 4; ++dt) {
      bf16x8 vb0 = *(const bf16x8*)(vb + vro[dt] + ((g ^ vxr[dt]) << 4));
      bf16x8 vb1 = *(const bf16x8*)(vb + vro[dt] + (((4 + g) ^ vxr[dt]) << 4));
      acc_o[dt] = __builtin_amdgcn_mfma_f32_16x16x32_bf16(a0.v, vb0, acc_o[dt], 0, 0, 0);
      acc_o[dt] = __builtin_amdgcn_mfma_f32_16x16x32_bf16(a1.v, vb1, acc_o[dt], 0, 0, 0);
    }

    __syncthreads();
    cur ^= 1;
  }

  l_run += __shfl_xor(l_run, 16);
  l_run += __shfl_xor(l_run, 32);

  float inv[4];
  #pragma unroll
  for (int r = 0; r < 4; ++r)
    inv[r] = 1.0f / __shfl(l_run, g * 4 + r);

  #pragma unroll
  for (int dt = 0; dt < 4; ++dt)
    #pragma unroll
    for (int r = 0; r < 4; ++r) {
      int row = b * SDIM + qloc + g * 4 + r;
      vals[(size_t)row * EMB + h * HDIM + dt * 16 + c] = f2bf(acc_o[dt][r] * inv[r]);
    }
}

extern "C" void kernel_launch(void* const* d_in, const int* in_sizes, int n_in,
                              void* d_out, int out_size, void* d_ws, size_t ws_size,
                              hipStream_t stream) {
  const float* x     = (const float*)d_in[0];
  const int*   mask  = (const int*)d_in[1];
  const float* wts   = (const float*)d_in[2];
  const float* W_qkv = (const float*)d_in[3];
  const float* b_qkv = (const float*)d_in[4];
  const float* W_o   = (const float*)d_in[5];
  const float* b_o   = (const float*)d_in[6];
  float* out = (float*)d_out;

  char* ws = (char*)d_ws;
  u16* xb   = (u16*)(ws);                     //  8 MB x bf16
  u16* wqb  = (u16*)(ws + (8ull  << 20));     //  6 MB W_qkv bf16
  u16* wob  = (u16*)(ws + (14ull << 20));     //  2 MB W_o bf16
  u16* Qh   = (u16*)(ws + (16ull << 20));     //  8 MB [bh][s][64]
  u16* Kh   = (u16*)(ws + (24ull << 20));     //  8 MB [bh][s][64]
  u16* Vt   = (u16*)(ws + (32ull << 20));     //  8 MB [bh][64][s]
  u16* valb = (u16*)(ws + (40ull << 20));     //  8 MB attn out bf16
  u16* wm3b = (u16*)d_out;                    //  8 MB scratch in d_out (overwritten by gemm_bt)

  cvt3_kernel<<<2048, 256, 0, stream>>>(x, W_qkv, W_o, xb, wqb, wob);

  gemm_qkv_wm3<<<256, 512, 0, stream>>>(xb, wqb, b_qkv, Qh, Kh, Vt, mask, wts, wm3b);

  attn_kernel<<<1024, 256, 0, stream>>>(Qh, Kh, Vt, wm3b, valb);

  dim3 g3(32, 8);
  gemm_bt<<<g3, 256, 0, stream>>>(valb, wob, b_o, out, BATCH * SDIM, EMB, KDIM);
}